// Round 11
// baseline (272.120 us; speedup 1.0000x reference)
//
#include <hip/hip_runtime.h>

#define NN 100000
#define NE 600000
#define NB_SCAN 98   // 98 * 1024 = 100352 >= NN

typedef __attribute__((ext_vector_type(8))) short short8v;   // 8 bf16 (4 VGPRs)
typedef __attribute__((ext_vector_type(4))) float float4v;   // MFMA acc

// bf16 helpers (RNE; inputs are finite)
__device__ __forceinline__ unsigned short f2b(float f) {
  unsigned u = __float_as_uint(f);
  unsigned r = u + 0x7fffu + ((u >> 16) & 1u);
  return (unsigned short)(r >> 16);
}
__device__ __forceinline__ float b2f(unsigned short s) {
  return __uint_as_float((unsigned)s << 16);
}
__device__ __forceinline__ float bf_lo(unsigned p) { return __uint_as_float(p << 16); }
__device__ __forceinline__ float bf_hi(unsigned p) { return __uint_as_float(p & 0xffff0000u); }

// ---------------- degree (int atomics) ----------------
__global__ void deg_kernel(const int* __restrict__ dst, int* __restrict__ deg) {
  int i = blockIdx.x * blockDim.x + threadIdx.x;
  int n = gridDim.x * blockDim.x;
  for (; i < NE; i += n) atomicAdd(&deg[dst[i]], 1);
}

// ---------------- W -> bf16 transposed: wt[n][k] = W[k][n] ----------------
__global__ void wprep_kernel(const float* __restrict__ W1, const float* __restrict__ W2,
                             const float* __restrict__ W3, unsigned short* __restrict__ wt1,
                             unsigned short* __restrict__ wt2, unsigned short* __restrict__ wt3) {
  int t = blockIdx.x * blockDim.x + threadIdx.x;
  if (t < 16384) {
    int n = t >> 7, k = t & 127; wt1[t] = f2b(W1[k * 128 + n]);
  } else if (t < 32768) {
    int i = t - 16384; int n = i >> 7, k = i & 127; wt2[i] = f2b(W2[k * 128 + n]);
  } else if (t < 40960) {
    int i = t - 32768; int n = i >> 7, k = i & 127; wt3[i] = f2b(W3[k * 64 + n]);
  }
}

// ---------------- hierarchical exclusive scan: deg -> off (+ fused dinv) ----------------
__global__ __launch_bounds__(1024) void scan_blocks(const int* __restrict__ deg,
                                                    int* __restrict__ off,
                                                    int* __restrict__ bsum,
                                                    float* __restrict__ dinv) {
  __shared__ int wsum[16];
  const int t = threadIdx.x, lane = t & 63, wv = t >> 6;
  const int i = blockIdx.x * 1024 + t;
  int v = (i < NN) ? deg[i] : 0;
  if (i < NN) dinv[i] = rsqrtf((float)v + 1.0f);
  int sv = v;
  #pragma unroll
  for (int d = 1; d < 64; d <<= 1) {
    int u = __shfl_up(sv, d, 64);
    if (lane >= d) sv += u;
  }
  if (lane == 63) wsum[wv] = sv;
  __syncthreads();
  if (t < 16) {
    int w0 = wsum[t];
    #pragma unroll
    for (int d = 1; d < 16; d <<= 1) {
      int u = __shfl_up(w0, d, 64);
      if (t >= d) w0 += u;
    }
    wsum[t] = w0;
  }
  __syncthreads();
  int excl = (wv ? wsum[wv - 1] : 0) + (sv - v);
  if (i < NN) off[i] = excl;
  if (t == 0) bsum[blockIdx.x] = wsum[15];
}

__global__ __launch_bounds__(128) void scan_bsum(int* __restrict__ bsum) {
  __shared__ int ws0;
  const int t = threadIdx.x, lane = t & 63, wv = t >> 6;
  int v = (t < NB_SCAN) ? bsum[t] : 0;
  int sv = v;
  #pragma unroll
  for (int d = 1; d < 64; d <<= 1) {
    int u = __shfl_up(sv, d, 64);
    if (lane >= d) sv += u;
  }
  if (wv == 0 && lane == 63) ws0 = sv;
  __syncthreads();
  int excl = (wv ? ws0 : 0) + (sv - v);
  if (t < NB_SCAN) bsum[t] = excl;
}

__global__ __launch_bounds__(1024) void scan_add(int* __restrict__ off,
                                                 const int* __restrict__ bsum) {
  int i = blockIdx.x * 1024 + threadIdx.x;
  if (i < NN) off[i] += bsum[blockIdx.x];
  if (i == 0) off[NN] = NE;
}

// ---------------- counting-sort fill: CSR edge list with precomputed coef ----------------
__global__ void fill_kernel(const int* __restrict__ src, const int* __restrict__ dst,
                            const float* __restrict__ dinv, const int* __restrict__ off,
                            int* __restrict__ cursor, int2* __restrict__ einfo) {
  int i = blockIdx.x * blockDim.x + threadIdx.x;
  int n = gridDim.x * blockDim.x;
  for (; i < NE; i += n) {
    int s = src[i], d = dst[i];
    int pos = off[d] + atomicAdd(&cursor[d], 1);
    einfo[pos] = make_int2(s, __float_as_int(dinv[s] * dinv[d]));
  }
}

// ---------------- MFMA GEMM: h[NN][NOUT] bf16 = in[NN][128] @ Wt^T ----------------
// 64 rows/block, 4 waves; bf16 LDS epilogue tile (17 KB) for high occupancy.
template<int NOUT, bool AF32>
__global__ __launch_bounds__(256) void mfma_gemm(
    const void* __restrict__ in_, const unsigned short* __restrict__ wt,
    unsigned short* __restrict__ h)
{
  constexpr int NCT = NOUT / 16;
  __shared__ unsigned short es16[64 * 136];   // row stride 272B (16B-aligned)
  const int t = threadIdx.x;
  const int w = t >> 6;
  const int l = t & 63;
  const int row0 = blockIdx.x * 64;

  int arow = row0 + w * 16 + (l & 15);
  if (arow > NN - 1) arow = NN - 1;
  const int kbase = (l >> 4) * 8;

  short8v a[4];
  if constexpr (AF32) {
    const float* inf = (const float*)in_;
    #pragma unroll
    for (int kt = 0; kt < 4; ++kt) {
      const float* p = inf + (size_t)arow * 128 + kt * 32 + kbase;
      float4 u0 = *(const float4*)p;
      float4 u1 = *(const float4*)(p + 4);
      short8v av;
      av[0] = (short)f2b(u0.x); av[1] = (short)f2b(u0.y);
      av[2] = (short)f2b(u0.z); av[3] = (short)f2b(u0.w);
      av[4] = (short)f2b(u1.x); av[5] = (short)f2b(u1.y);
      av[6] = (short)f2b(u1.z); av[7] = (short)f2b(u1.w);
      a[kt] = av;
    }
  } else {
    const unsigned short* inb = (const unsigned short*)in_;
    #pragma unroll
    for (int kt = 0; kt < 4; ++kt)
      a[kt] = *(const short8v*)(inb + (size_t)arow * 128 + kt * 32 + kbase);
  }

  const int bofs = (l & 15) * 128 + kbase;

  float4v acc[NCT];
  #pragma unroll
  for (int c = 0; c < NCT; ++c) acc[c] = (float4v){0.f, 0.f, 0.f, 0.f};

  #pragma unroll
  for (int kt = 0; kt < 4; ++kt) {
    #pragma unroll
    for (int c = 0; c < NCT; ++c) {
      short8v b = *(const short8v*)(wt + (size_t)c * 16 * 128 + bofs + kt * 32);
      acc[c] = __builtin_amdgcn_mfma_f32_16x16x32_bf16(a[kt], b, acc[c], 0, 0, 0);
    }
  }

  // epilogue: acc -> bf16 -> LDS -> coalesced uint4 stores
  const int q = l >> 4, c16 = l & 15;
  #pragma unroll
  for (int c = 0; c < NCT; ++c) {
    #pragma unroll
    for (int r = 0; r < 4; ++r)
      es16[(w * 16 + q * 4 + r) * 136 + c * 16 + c16] = f2b(acc[c][r]);
  }
  __syncthreads();
  constexpr int GPR = NOUT / 8;   // uint4 (8 bf16) groups per row: 16 or 8
  #pragma unroll
  for (int it = 0; it < 64 * GPR / 256; ++it) {
    int f = t + it * 256;
    int r = f / GPR, g = f % GPR;
    int row = row0 + r;
    if (row < NN)
      *(uint4*)(h + (size_t)row * NOUT + g * 8) = *(const uint4*)&es16[r * 136 + g * 8];
  }
}

// ---------------- aggregate (quad-edge): out[d] = b + dinv^2*h[d] + sum coef*h[src] ----------------
template<int NOUT, bool BF16RELU>
__global__ __launch_bounds__(256) void agg_kernel(
    const unsigned short* __restrict__ h, const int* __restrict__ off,
    const int2* __restrict__ einfo, const float* __restrict__ dinv,
    const float* __restrict__ bias, void* __restrict__ out_)
{
  constexpr int LPR = NOUT / 8;     // lanes per row (uint4): 16 or 8
  constexpr int GS  = 64 / LPR;     // edge slots per wave: 4 or 8
  const int w = (int)((blockIdx.x * 256 + threadIdx.x) >> 6);
  if (w >= NN) return;
  const int lane = threadIdx.x & 63;
  const int g = lane / LPR;
  const int c = lane % LPR;
  const int n0 = off[w], n1 = off[w + 1];
  const uint4* hu4 = (const uint4*)h;

  float acc[8];
  if (g == 0) {
    const float di = dinv[w];
    const float di2 = di * di;
    uint4 sv = hu4[(size_t)w * LPR + c];
    const float4* b4 = (const float4*)bias;
    float4 bl = b4[c * 2], bh = b4[c * 2 + 1];
    acc[0] = fmaf(bf_lo(sv.x), di2, bl.x);
    acc[1] = fmaf(bf_hi(sv.x), di2, bl.y);
    acc[2] = fmaf(bf_lo(sv.y), di2, bl.z);
    acc[3] = fmaf(bf_hi(sv.y), di2, bl.w);
    acc[4] = fmaf(bf_lo(sv.z), di2, bh.x);
    acc[5] = fmaf(bf_hi(sv.z), di2, bh.y);
    acc[6] = fmaf(bf_lo(sv.w), di2, bh.z);
    acc[7] = fmaf(bf_hi(sv.w), di2, bh.w);
  } else {
    #pragma unroll
    for (int j = 0; j < 8; ++j) acc[j] = 0.f;
  }

  for (int e = n0; e < n1; e += 2 * GS) {
    int e0 = e + g, e1 = e + GS + g;
    bool ok0 = e0 < n1, ok1 = e1 < n1;
    int2 s0 = einfo[ok0 ? e0 : n0];
    int2 s1 = einfo[ok1 ? e1 : n0];
    float c0 = ok0 ? __int_as_float(s0.y) : 0.f;
    float c1 = ok1 ? __int_as_float(s1.y) : 0.f;
    uint4 v0 = hu4[(size_t)s0.x * LPR + c];
    uint4 v1 = hu4[(size_t)s1.x * LPR + c];
    acc[0] = fmaf(bf_lo(v0.x), c0, acc[0]);
    acc[1] = fmaf(bf_hi(v0.x), c0, acc[1]);
    acc[2] = fmaf(bf_lo(v0.y), c0, acc[2]);
    acc[3] = fmaf(bf_hi(v0.y), c0, acc[3]);
    acc[4] = fmaf(bf_lo(v0.z), c0, acc[4]);
    acc[5] = fmaf(bf_hi(v0.z), c0, acc[5]);
    acc[6] = fmaf(bf_lo(v0.w), c0, acc[6]);
    acc[7] = fmaf(bf_hi(v0.w), c0, acc[7]);
    acc[0] = fmaf(bf_lo(v1.x), c1, acc[0]);
    acc[1] = fmaf(bf_hi(v1.x), c1, acc[1]);
    acc[2] = fmaf(bf_lo(v1.y), c1, acc[2]);
    acc[3] = fmaf(bf_hi(v1.y), c1, acc[3]);
    acc[4] = fmaf(bf_lo(v1.z), c1, acc[4]);
    acc[5] = fmaf(bf_hi(v1.z), c1, acc[5]);
    acc[6] = fmaf(bf_lo(v1.w), c1, acc[6]);
    acc[7] = fmaf(bf_hi(v1.w), c1, acc[7]);
  }

  #pragma unroll
  for (int j = 0; j < 8; ++j) {
    #pragma unroll
    for (int m = LPR; m < 64; m <<= 1)
      acc[j] += __shfl_xor(acc[j], m, 64);
  }

  if (g == 0) {
    if constexpr (BF16RELU) {
      uint4 o;
      o.x = (unsigned)f2b(fmaxf(acc[0], 0.f)) | ((unsigned)f2b(fmaxf(acc[1], 0.f)) << 16);
      o.y = (unsigned)f2b(fmaxf(acc[2], 0.f)) | ((unsigned)f2b(fmaxf(acc[3], 0.f)) << 16);
      o.z = (unsigned)f2b(fmaxf(acc[4], 0.f)) | ((unsigned)f2b(fmaxf(acc[5], 0.f)) << 16);
      o.w = (unsigned)f2b(fmaxf(acc[6], 0.f)) | ((unsigned)f2b(fmaxf(acc[7], 0.f)) << 16);
      ((uint4*)out_)[(size_t)w * LPR + c] = o;
    } else {
      float4 o0, o1;
      o0.x = acc[0]; o0.y = acc[1]; o0.z = acc[2]; o0.w = acc[3];
      o1.x = acc[4]; o1.y = acc[5]; o1.z = acc[6]; o1.w = acc[7];
      ((float4*)out_)[(size_t)w * LPR * 2 + c * 2]     = o0;
      ((float4*)out_)[(size_t)w * LPR * 2 + c * 2 + 1] = o1;
    }
  }
}

extern "C" void kernel_launch(void* const* d_in, const int* in_sizes, int n_in,
                              void* d_out, int out_size, void* d_ws, size_t ws_size,
                              hipStream_t stream) {
  const float* x  = (const float*)d_in[0];
  const int*   ei = (const int*)d_in[1];
  const float* W1 = (const float*)d_in[2];
  const float* b1 = (const float*)d_in[3];
  const float* W2 = (const float*)d_in[4];
  const float* b2 = (const float*)d_in[5];
  const float* W3 = (const float*)d_in[6];
  const float* b3 = (const float*)d_in[7];
  float* out = (float*)d_out;

  const int* src = ei;
  const int* dst = ei + NE;

  // workspace layout (float elements)
  float* ws = (float*)d_ws;
  int*   deg    = (int*)ws;                         // NN
  float* dinv   = ws + NN;                          // NN
  int*   off    = (int*)(ws + 2 * NN);              // NN+4
  int*   cursor = (int*)(ws + 3 * NN + 4);          // NN
  int*   bsum   = (int*)(ws + 4 * NN + 4);          // 128
  int2*  einfo  = (int2*)(ws + 4 * NN + 132);       // NE int2
  unsigned short* wt1 = (unsigned short*)(ws + 4 * NN + 132 + 2 * NE);  // 16384 bf16
  unsigned short* wt2 = wt1 + 16384;
  unsigned short* wt3 = wt2 + 16384;
  unsigned short* hA  = (unsigned short*)(ws + 4 * NN + 132 + 2 * NE + 20480); // NN*128 bf16
  unsigned short* hB  = hA + (size_t)NN * 128;                                 // NN*128 bf16

  hipMemsetAsync(deg, 0, NN * sizeof(int), stream);
  hipMemsetAsync(cursor, 0, NN * sizeof(int), stream);
  wprep_kernel<<<160, 256, 0, stream>>>(W1, W2, W3, wt1, wt2, wt3);
  deg_kernel<<<1024, 256, 0, stream>>>(dst, deg);
  scan_blocks<<<NB_SCAN, 1024, 0, stream>>>(deg, off, bsum, dinv);
  scan_bsum<<<1, 128, 0, stream>>>(bsum);
  scan_add<<<NB_SCAN, 1024, 0, stream>>>(off, bsum);
  fill_kernel<<<1024, 256, 0, stream>>>(src, dst, dinv, off, cursor, einfo);

  const int AGG_BLOCKS = (NN * 64 + 255) / 256;   // one wave per node
  const int GEMM_BLOCKS = (NN + 63) / 64;

  // layer 1
  mfma_gemm<128, true><<<GEMM_BLOCKS, 256, 0, stream>>>(x, wt1, hA);
  agg_kernel<128, true><<<AGG_BLOCKS, 256, 0, stream>>>(hA, off, einfo, dinv, b1, hB);
  // layer 2
  mfma_gemm<128, false><<<GEMM_BLOCKS, 256, 0, stream>>>(hB, wt2, hA);
  agg_kernel<128, true><<<AGG_BLOCKS, 256, 0, stream>>>(hA, off, einfo, dinv, b2, hB);
  // layer 3 (64-wide, f32 final out)
  mfma_gemm<64, false><<<GEMM_BLOCKS, 256, 0, stream>>>(hB, wt3, hA);
  agg_kernel<64, false><<<AGG_BLOCKS, 256, 0, stream>>>(hA, off, einfo, dinv, b3, out);
}

// Round 12
// 220.352 us; speedup vs baseline: 1.2349x; 1.2349x over previous
//
#include <hip/hip_runtime.h>

#define NN 100000
#define NE 600000
#define NB_SCAN 98   // 98 * 1024 = 100352 >= NN

typedef __attribute__((ext_vector_type(8))) short short8v;   // 8 bf16 (4 VGPRs)
typedef __attribute__((ext_vector_type(4))) float float4v;   // MFMA acc

// bf16 helpers (RNE; inputs are finite)
__device__ __forceinline__ unsigned short f2b(float f) {
  unsigned u = __float_as_uint(f);
  unsigned r = u + 0x7fffu + ((u >> 16) & 1u);
  return (unsigned short)(r >> 16);
}
__device__ __forceinline__ float b2f(unsigned short s) {
  return __uint_as_float((unsigned)s << 16);
}
__device__ __forceinline__ float bf_lo(unsigned p) { return __uint_as_float(p << 16); }
__device__ __forceinline__ float bf_hi(unsigned p) { return __uint_as_float(p & 0xffff0000u); }

// ---------------- degree (int atomics) ----------------
__global__ void deg_kernel(const int* __restrict__ dst, int* __restrict__ deg) {
  int i = blockIdx.x * blockDim.x + threadIdx.x;
  int n = gridDim.x * blockDim.x;
  for (; i < NE; i += n) atomicAdd(&deg[dst[i]], 1);
}

// ---------------- W -> bf16 transposed: wt[n][k] = W[k][n] ----------------
__global__ void wprep_kernel(const float* __restrict__ W1, const float* __restrict__ W2,
                             const float* __restrict__ W3, unsigned short* __restrict__ wt1,
                             unsigned short* __restrict__ wt2, unsigned short* __restrict__ wt3) {
  int t = blockIdx.x * blockDim.x + threadIdx.x;
  if (t < 16384) {
    int n = t >> 7, k = t & 127; wt1[t] = f2b(W1[k * 128 + n]);
  } else if (t < 32768) {
    int i = t - 16384; int n = i >> 7, k = i & 127; wt2[i] = f2b(W2[k * 128 + n]);
  } else if (t < 40960) {
    int i = t - 32768; int n = i >> 7, k = i & 127; wt3[i] = f2b(W3[k * 64 + n]);
  }
}

// ---------------- hierarchical exclusive scan: deg -> off (+ fused dinv) ----------------
__global__ __launch_bounds__(1024) void scan_blocks(const int* __restrict__ deg,
                                                    int* __restrict__ off,
                                                    int* __restrict__ bsum,
                                                    float* __restrict__ dinv) {
  __shared__ int wsum[16];
  const int t = threadIdx.x, lane = t & 63, wv = t >> 6;
  const int i = blockIdx.x * 1024 + t;
  int v = (i < NN) ? deg[i] : 0;
  if (i < NN) dinv[i] = rsqrtf((float)v + 1.0f);
  int sv = v;
  #pragma unroll
  for (int d = 1; d < 64; d <<= 1) {
    int u = __shfl_up(sv, d, 64);
    if (lane >= d) sv += u;
  }
  if (lane == 63) wsum[wv] = sv;
  __syncthreads();
  if (t < 16) {
    int w0 = wsum[t];
    #pragma unroll
    for (int d = 1; d < 16; d <<= 1) {
      int u = __shfl_up(w0, d, 64);
      if (t >= d) w0 += u;
    }
    wsum[t] = w0;
  }
  __syncthreads();
  int excl = (wv ? wsum[wv - 1] : 0) + (sv - v);
  if (i < NN) off[i] = excl;
  if (t == 0) bsum[blockIdx.x] = wsum[15];
}

__global__ __launch_bounds__(128) void scan_bsum(int* __restrict__ bsum) {
  __shared__ int ws0;
  const int t = threadIdx.x, lane = t & 63, wv = t >> 6;
  int v = (t < NB_SCAN) ? bsum[t] : 0;
  int sv = v;
  #pragma unroll
  for (int d = 1; d < 64; d <<= 1) {
    int u = __shfl_up(sv, d, 64);
    if (lane >= d) sv += u;
  }
  if (wv == 0 && lane == 63) ws0 = sv;
  __syncthreads();
  int excl = (wv ? ws0 : 0) + (sv - v);
  if (t < NB_SCAN) bsum[t] = excl;
}

__global__ __launch_bounds__(1024) void scan_add(int* __restrict__ off,
                                                 const int* __restrict__ bsum) {
  int i = blockIdx.x * 1024 + threadIdx.x;
  if (i < NN) off[i] += bsum[blockIdx.x];
  if (i == 0) off[NN] = NE;
}

// ---------------- counting-sort fill: CSR edge list with precomputed coef ----------------
__global__ void fill_kernel(const int* __restrict__ src, const int* __restrict__ dst,
                            const float* __restrict__ dinv, const int* __restrict__ off,
                            int* __restrict__ cursor, int2* __restrict__ einfo) {
  int i = blockIdx.x * blockDim.x + threadIdx.x;
  int n = gridDim.x * blockDim.x;
  for (; i < NE; i += n) {
    int s = src[i], d = dst[i];
    int pos = off[d] + atomicAdd(&cursor[d], 1);
    einfo[pos] = make_int2(s, __float_as_int(dinv[s] * dinv[d]));
  }
}

// ---------------- MFMA GEMM v3: B in LDS, grid-stride tiles, A-prefetch ----------------
// 512 blocks x 256 thr; wt staged to LDS once (padded 136 stride); each wave
// owns 16 rows/tile, loops tiles with next-tile A prefetched before MFMAs.
// Epilogue via PER-WAVE LDS slice (same-wave DS is in-order -> no barrier).
template<int NOUT, bool AF32>
__global__ __launch_bounds__(256) void mfma_gemm(
    const void* __restrict__ in_, const unsigned short* __restrict__ wt,
    unsigned short* __restrict__ h, int ntiles)
{
  constexpr int NCT = NOUT / 16;
  constexpr int LDW = 136;                 // 272B row stride: 16B-aligned, ~2-way banks
  __shared__ unsigned short wl[NOUT * LDW];
  __shared__ unsigned short es[4 * 16 * LDW];
  const int t = threadIdx.x;
  const int w = t >> 6, l = t & 63;
  const int r16 = l & 15, kbase = (l >> 4) * 8;

  // stage wt -> LDS (coalesced uint4)
  const uint4* wt4 = (const uint4*)wt;
  #pragma unroll
  for (int i = 0; i < NOUT * 16 / 256; ++i) {
    int idx = t + i * 256;
    int n = idx >> 4, g = idx & 15;
    *(uint4*)&wl[n * LDW + g * 8] = wt4[idx];
  }
  __syncthreads();

  unsigned short* esw = &es[w * 16 * LDW];
  const float* inf = (const float*)in_;
  const unsigned short* inb = (const unsigned short*)in_;

  int tile = blockIdx.x;
  if (tile >= ntiles) return;

  float4  nf[8];
  short8v nb[4];
  {
    int grow = tile * 64 + w * 16 + r16; if (grow > NN - 1) grow = NN - 1;
    if constexpr (AF32) {
      #pragma unroll
      for (int kt = 0; kt < 4; ++kt) {
        const float* p = inf + (size_t)grow * 128 + kt * 32 + kbase;
        nf[kt * 2] = *(const float4*)p; nf[kt * 2 + 1] = *(const float4*)(p + 4);
      }
    } else {
      #pragma unroll
      for (int kt = 0; kt < 4; ++kt)
        nb[kt] = *(const short8v*)(inb + (size_t)grow * 128 + kt * 32 + kbase);
    }
  }

  while (true) {
    // consume prefetched A (convert if f32)
    short8v a[4];
    if constexpr (AF32) {
      #pragma unroll
      for (int kt = 0; kt < 4; ++kt) {
        float4 u0 = nf[kt * 2], u1 = nf[kt * 2 + 1];
        short8v av;
        av[0] = (short)f2b(u0.x); av[1] = (short)f2b(u0.y);
        av[2] = (short)f2b(u0.z); av[3] = (short)f2b(u0.w);
        av[4] = (short)f2b(u1.x); av[5] = (short)f2b(u1.y);
        av[6] = (short)f2b(u1.z); av[7] = (short)f2b(u1.w);
        a[kt] = av;
      }
    } else {
      #pragma unroll
      for (int kt = 0; kt < 4; ++kt) a[kt] = nb[kt];
    }

    // issue next-tile A loads (latency hides under MFMAs+epilogue below)
    int next = tile + gridDim.x;
    if (next < ntiles) {
      int grow = next * 64 + w * 16 + r16; if (grow > NN - 1) grow = NN - 1;
      if constexpr (AF32) {
        #pragma unroll
        for (int kt = 0; kt < 4; ++kt) {
          const float* p = inf + (size_t)grow * 128 + kt * 32 + kbase;
          nf[kt * 2] = *(const float4*)p; nf[kt * 2 + 1] = *(const float4*)(p + 4);
        }
      } else {
        #pragma unroll
        for (int kt = 0; kt < 4; ++kt)
          nb[kt] = *(const short8v*)(inb + (size_t)grow * 128 + kt * 32 + kbase);
      }
    }

    float4v acc[NCT];
    #pragma unroll
    for (int c = 0; c < NCT; ++c) acc[c] = (float4v){0.f, 0.f, 0.f, 0.f};
    #pragma unroll
    for (int kt = 0; kt < 4; ++kt) {
      #pragma unroll
      for (int c = 0; c < NCT; ++c) {
        short8v b = *(const short8v*)&wl[(c * 16 + r16) * LDW + kt * 32 + kbase];
        acc[c] = __builtin_amdgcn_mfma_f32_16x16x32_bf16(a[kt], b, acc[c], 0, 0, 0);
      }
    }

    // per-wave epilogue: b16 scatter -> in-order DS -> uint4 coalesced stores
    const int q = l >> 4;
    #pragma unroll
    for (int c = 0; c < NCT; ++c) {
      #pragma unroll
      for (int r = 0; r < 4; ++r)
        esw[(q * 4 + r) * LDW + c * 16 + r16] = f2b(acc[c][r]);
    }
    constexpr int GPR2 = NOUT / 8;
    const int row0 = tile * 64 + w * 16;
    #pragma unroll
    for (int i = 0; i < 16 * GPR2 / 64; ++i) {
      int f = l + i * 64;
      int r = f / GPR2, g = f % GPR2;
      int row = row0 + r;
      if (row < NN)
        *(uint4*)(h + (size_t)row * NOUT + g * 8) = *(const uint4*)&esw[r * LDW + g * 8];
    }

    if (next >= ntiles) break;
    tile = next;
  }
}

// ---------------- aggregate (quad-edge): out[d] = b + dinv^2*h[d] + sum coef*h[src] ----------------
template<int NOUT, bool BF16RELU>
__global__ __launch_bounds__(256) void agg_kernel(
    const unsigned short* __restrict__ h, const int* __restrict__ off,
    const int2* __restrict__ einfo, const float* __restrict__ dinv,
    const float* __restrict__ bias, void* __restrict__ out_)
{
  constexpr int LPR = NOUT / 8;     // lanes per row (uint4): 16 or 8
  constexpr int GS  = 64 / LPR;     // edge slots per wave: 4 or 8
  const int w = (int)((blockIdx.x * 256 + threadIdx.x) >> 6);
  if (w >= NN) return;
  const int lane = threadIdx.x & 63;
  const int g = lane / LPR;
  const int c = lane % LPR;
  const int n0 = off[w], n1 = off[w + 1];
  const uint4* hu4 = (const uint4*)h;

  float acc[8];
  if (g == 0) {
    const float di = dinv[w];
    const float di2 = di * di;
    uint4 sv = hu4[(size_t)w * LPR + c];
    const float4* b4 = (const float4*)bias;
    float4 bl = b4[c * 2], bh = b4[c * 2 + 1];
    acc[0] = fmaf(bf_lo(sv.x), di2, bl.x);
    acc[1] = fmaf(bf_hi(sv.x), di2, bl.y);
    acc[2] = fmaf(bf_lo(sv.y), di2, bl.z);
    acc[3] = fmaf(bf_hi(sv.y), di2, bl.w);
    acc[4] = fmaf(bf_lo(sv.z), di2, bh.x);
    acc[5] = fmaf(bf_hi(sv.z), di2, bh.y);
    acc[6] = fmaf(bf_lo(sv.w), di2, bh.z);
    acc[7] = fmaf(bf_hi(sv.w), di2, bh.w);
  } else {
    #pragma unroll
    for (int j = 0; j < 8; ++j) acc[j] = 0.f;
  }

  for (int e = n0; e < n1; e += 2 * GS) {
    int e0 = e + g, e1 = e + GS + g;
    bool ok0 = e0 < n1, ok1 = e1 < n1;
    int2 s0 = einfo[ok0 ? e0 : n0];
    int2 s1 = einfo[ok1 ? e1 : n0];
    float c0 = ok0 ? __int_as_float(s0.y) : 0.f;
    float c1 = ok1 ? __int_as_float(s1.y) : 0.f;
    uint4 v0 = hu4[(size_t)s0.x * LPR + c];
    uint4 v1 = hu4[(size_t)s1.x * LPR + c];
    acc[0] = fmaf(bf_lo(v0.x), c0, acc[0]);
    acc[1] = fmaf(bf_hi(v0.x), c0, acc[1]);
    acc[2] = fmaf(bf_lo(v0.y), c0, acc[2]);
    acc[3] = fmaf(bf_hi(v0.y), c0, acc[3]);
    acc[4] = fmaf(bf_lo(v0.z), c0, acc[4]);
    acc[5] = fmaf(bf_hi(v0.z), c0, acc[5]);
    acc[6] = fmaf(bf_lo(v0.w), c0, acc[6]);
    acc[7] = fmaf(bf_hi(v0.w), c0, acc[7]);
    acc[0] = fmaf(bf_lo(v1.x), c1, acc[0]);
    acc[1] = fmaf(bf_hi(v1.x), c1, acc[1]);
    acc[2] = fmaf(bf_lo(v1.y), c1, acc[2]);
    acc[3] = fmaf(bf_hi(v1.y), c1, acc[3]);
    acc[4] = fmaf(bf_lo(v1.z), c1, acc[4]);
    acc[5] = fmaf(bf_hi(v1.z), c1, acc[5]);
    acc[6] = fmaf(bf_lo(v1.w), c1, acc[6]);
    acc[7] = fmaf(bf_hi(v1.w), c1, acc[7]);
  }

  #pragma unroll
  for (int j = 0; j < 8; ++j) {
    #pragma unroll
    for (int m = LPR; m < 64; m <<= 1)
      acc[j] += __shfl_xor(acc[j], m, 64);
  }

  if (g == 0) {
    if constexpr (BF16RELU) {
      uint4 o;
      o.x = (unsigned)f2b(fmaxf(acc[0], 0.f)) | ((unsigned)f2b(fmaxf(acc[1], 0.f)) << 16);
      o.y = (unsigned)f2b(fmaxf(acc[2], 0.f)) | ((unsigned)f2b(fmaxf(acc[3], 0.f)) << 16);
      o.z = (unsigned)f2b(fmaxf(acc[4], 0.f)) | ((unsigned)f2b(fmaxf(acc[5], 0.f)) << 16);
      o.w = (unsigned)f2b(fmaxf(acc[6], 0.f)) | ((unsigned)f2b(fmaxf(acc[7], 0.f)) << 16);
      ((uint4*)out_)[(size_t)w * LPR + c] = o;
    } else {
      float4 o0, o1;
      o0.x = acc[0]; o0.y = acc[1]; o0.z = acc[2]; o0.w = acc[3];
      o1.x = acc[4]; o1.y = acc[5]; o1.z = acc[6]; o1.w = acc[7];
      ((float4*)out_)[(size_t)w * LPR * 2 + c * 2]     = o0;
      ((float4*)out_)[(size_t)w * LPR * 2 + c * 2 + 1] = o1;
    }
  }
}

extern "C" void kernel_launch(void* const* d_in, const int* in_sizes, int n_in,
                              void* d_out, int out_size, void* d_ws, size_t ws_size,
                              hipStream_t stream) {
  const float* x  = (const float*)d_in[0];
  const int*   ei = (const int*)d_in[1];
  const float* W1 = (const float*)d_in[2];
  const float* b1 = (const float*)d_in[3];
  const float* W2 = (const float*)d_in[4];
  const float* b2 = (const float*)d_in[5];
  const float* W3 = (const float*)d_in[6];
  const float* b3 = (const float*)d_in[7];
  float* out = (float*)d_out;

  const int* src = ei;
  const int* dst = ei + NE;

  // workspace layout (float elements)
  float* ws = (float*)d_ws;
  int*   deg    = (int*)ws;                         // NN
  float* dinv   = ws + NN;                          // NN
  int*   off    = (int*)(ws + 2 * NN);              // NN+4
  int*   cursor = (int*)(ws + 3 * NN + 4);          // NN
  int*   bsum   = (int*)(ws + 4 * NN + 4);          // 128
  int2*  einfo  = (int2*)(ws + 4 * NN + 132);       // NE int2
  unsigned short* wt1 = (unsigned short*)(ws + 4 * NN + 132 + 2 * NE);  // 16384 bf16
  unsigned short* wt2 = wt1 + 16384;
  unsigned short* wt3 = wt2 + 16384;
  unsigned short* hA  = (unsigned short*)(ws + 4 * NN + 132 + 2 * NE + 20480); // NN*128 bf16
  unsigned short* hB  = hA + (size_t)NN * 128;                                 // NN*128 bf16

  hipMemsetAsync(deg, 0, NN * sizeof(int), stream);
  hipMemsetAsync(cursor, 0, NN * sizeof(int), stream);
  wprep_kernel<<<160, 256, 0, stream>>>(W1, W2, W3, wt1, wt2, wt3);
  deg_kernel<<<1024, 256, 0, stream>>>(dst, deg);
  scan_blocks<<<NB_SCAN, 1024, 0, stream>>>(deg, off, bsum, dinv);
  scan_bsum<<<1, 128, 0, stream>>>(bsum);
  scan_add<<<NB_SCAN, 1024, 0, stream>>>(off, bsum);
  fill_kernel<<<1024, 256, 0, stream>>>(src, dst, dinv, off, cursor, einfo);

  const int AGG_BLOCKS = (NN * 64 + 255) / 256;   // one wave per node
  const int NT = (NN + 63) / 64;                  // 1563 row tiles
  const int GEMM_GRID = 512;                      // 2 blocks/CU, ~3 tiles each

  // layer 1
  mfma_gemm<128, true><<<GEMM_GRID, 256, 0, stream>>>(x, wt1, hA, NT);
  agg_kernel<128, true><<<AGG_BLOCKS, 256, 0, stream>>>(hA, off, einfo, dinv, b1, hB);
  // layer 2
  mfma_gemm<128, false><<<GEMM_GRID, 256, 0, stream>>>(hB, wt2, hA, NT);
  agg_kernel<128, true><<<AGG_BLOCKS, 256, 0, stream>>>(hA, off, einfo, dinv, b2, hB);
  // layer 3 (64-wide, f32 final out)
  mfma_gemm<64, false><<<GEMM_GRID, 256, 0, stream>>>(hB, wt3, hA, NT);
  agg_kernel<64, false><<<AGG_BLOCKS, 256, 0, stream>>>(hA, off, einfo, dinv, b3, out);
}